// Round 7
// baseline (354.209 us; speedup 1.0000x reference)
//
#include <hip/hip_runtime.h>

// SpearmanCorrelationLoss on MI355X (gfx950) — R7
//
// Math: double-argsort ranks are a permutation of 1..N per column, so
// mean/var of ranks are exact constants; only S = Sum(rank_p*rank_t) needed:
//   corr_c = (S/N - 8192.5^2) / ((N^2-1)/12 + 2*EPS),  out = -mean_c(corr_c)
//
// Histogram ranking: bucket = floor(sigmoid(1.702*x)*8192) ~ Gaussian CDF ->
// near-uniform buckets (lambda ~2.15). rank(x) = P[b(x)] + #{y in bucket: y<x}
// (strict-less = lower_bound tie semantics; error ~1e-10 on output).
//
// R7 vs R6 (232 us total; main kernel memory-bound at 51% HBM peak):
// the transpose+workspace design carried >=384 MB/iter of hidden HBM traffic
// (128 MB ws poison + 128 MB transpose write + 128 MB transpose read) that
// evicted L3 and quadrupled the main kernel's FETCH. R7 removes the
// transpose and ALL workspace use: direct strided column reads from the
// row-major inputs. R1 measured this exact access pattern at FETCH ~= logical
// reads (L3 absorbs the 16x raw over-fetch: inputs 128 MB < 256 MB L3, each
// 64 B line shared by 16 column-blocks). Logical reads here: 128 MB total.
// One dispatch + 4-byte memset.

#define N_ROWS 16384
#define N_COLS 512
#define NT 1024
#define PT 16            // elements per thread
#define NBINS 8192
#define NWORDS (NBINS / 2)   // packed u16 cursor words

__device__ __forceinline__ unsigned f2key(float x) {
    // order-preserving fp32 -> u32 (no NaNs in input)
    unsigned u = __float_as_uint(x);
    return (u & 0x80000000u) ? ~u : (u | 0x80000000u);
}

// monotone approx Gaussian-CDF bucket: sigma(1.702x) = 1/(1+2^(-2.4554x))
__device__ __forceinline__ int f2bucket(float f) {
    float e = __builtin_amdgcn_exp2f(-2.4554f * f);   // v_exp_f32
    float s = __builtin_amdgcn_rcpf(1.0f + e);        // v_rcp_f32
    int b = (int)(s * (float)NBINS);
    return b < 0 ? 0 : (b > NBINS - 1 ? NBINS - 1 : b);
}

__global__ __launch_bounds__(NT, 8)
void spearman_col_kernel(const float* __restrict__ A, const float* __restrict__ B,
                         float* __restrict__ out) {
    __shared__ unsigned cursor[NWORDS];                  // 16 KB (u16-packed)
    __shared__ __align__(16) unsigned keys_sh[N_ROWS];   // 64 KB; total 80 KB
    const int col = blockIdx.x;
    const int tid = threadIdx.x;
    const int lane = tid & 63;
    const int wv = tid >> 6;

    unsigned rp2[PT / 2];          // packed u16 pred ranks (0-based, <16384)
    unsigned long long acc = 0;

    for (int phase = 0; phase < 2; ++phase) {
        const float* src = (phase == 0) ? A : B;

        // ---- load 16 elements (strided; L3-served) ----
        unsigned key[PT];
        unsigned bkt2[PT / 2];     // packed u16 buckets
        #pragma unroll
        for (int s = 0; s < PT; s += 2) {
            float f0 = src[(size_t)(tid + (s+0) * NT) * N_COLS + col];
            float f1 = src[(size_t)(tid + (s+1) * NT) * N_COLS + col];
            key[s]   = f2key(f0);
            key[s+1] = f2key(f1);
            bkt2[s/2] = (unsigned)f2bucket(f0) | ((unsigned)f2bucket(f1) << 16);
        }

        // ---- zero packed histogram ----
        __syncthreads();   // previous phase's keys_sh/cursor readers done
        ((uint4*)cursor)[tid] = make_uint4(0u, 0u, 0u, 0u);
        __syncthreads();

        // ---- histogram: +1 into the u16 half of word b>>1 ----
        #pragma unroll
        for (int s = 0; s < PT; ++s) {
            unsigned b = (bkt2[s/2] >> ((s & 1) * 16)) & 0xFFFFu;
            atomicAdd(&cursor[b >> 1], 1u << ((b & 1) * 16));
        }
        __syncthreads();

        // ---- exclusive prefix over 8192 u16 bins, wave-shuffle scan ----
        {
            unsigned* wtot = keys_sh;            // [0..15], keys_sh dead here
            uint4 h = ((uint4*)cursor)[tid];     // 4 words = 8 bins
            unsigned c0 = (h.x & 0xFFFFu), c1 = (h.x >> 16);
            unsigned c2 = (h.y & 0xFFFFu), c3 = (h.y >> 16);
            unsigned c4 = (h.z & 0xFFFFu), c5 = (h.z >> 16);
            unsigned c6 = (h.w & 0xFFFFu), c7 = (h.w >> 16);
            unsigned mysum = c0 + c1 + c2 + c3 + c4 + c5 + c6 + c7;
            unsigned incl = mysum;
            #pragma unroll
            for (int off = 1; off < 64; off <<= 1) {
                unsigned v = __shfl_up(incl, off, 64);
                if (lane >= off) incl += v;
            }
            if (lane == 63) wtot[wv] = incl;
            __syncthreads();
            if (tid < 16) {
                unsigned in2 = wtot[tid];
                #pragma unroll
                for (int off = 1; off < 16; off <<= 1) {
                    unsigned q = __shfl_up(in2, off, 64);
                    if (tid >= off) in2 += q;
                }
                wtot[tid] = in2;
            }
            __syncthreads();
            unsigned r = ((wv == 0) ? 0u : wtot[wv - 1]) + incl - mysum;
            uint4 o;
            o.x = r | ((r + c0) << 16); r += c0 + c1;
            o.y = r | ((r + c2) << 16); r += c2 + c3;
            o.z = r | ((r + c4) << 16); r += c4 + c5;
            o.w = r | ((r + c6) << 16); r += c6 + c7;
            ((uint4*)cursor)[tid] = o;
        }
        __syncthreads();   // wtot reads done before scatter overwrites keys_sh

        // ---- scatter keys into bucket slices (packed-half atomicAdd) ----
        #pragma unroll
        for (int s = 0; s < PT; ++s) {
            unsigned b = (bkt2[s/2] >> ((s & 1) * 16)) & 0xFFFFu;
            unsigned old = atomicAdd(&cursor[b >> 1], 1u << ((b & 1) * 16));
            unsigned slot = (old >> ((b & 1) * 16)) & 0xFFFFu;
            keys_sh[slot] = key[s];
        }
        __syncthreads();   // after this: half b of cursor == P[b+1]

        // ---- rank: P[b] + strict-less count within slice ----
        const unsigned short* cur16 = (const unsigned short*)cursor;
        #pragma unroll
        for (int s = 0; s < PT; ++s) {
            unsigned b = (bkt2[s/2] >> ((s & 1) * 16)) & 0xFFFFu;
            unsigned k = key[s];
            unsigned lo = (b == 0) ? 0u : (unsigned)cur16[b - 1];
            unsigned hi = (unsigned)cur16[b];
            unsigned r = lo;                       // P[b]
            for (unsigned j = lo; j < hi; ++j)
                r += (keys_sh[j] < k) ? 1u : 0u;
            if (phase == 0) {
                if ((s & 1) == 0) rp2[s/2] = r;
                else              rp2[s/2] |= (r << 16);
            } else {
                unsigned rp = (rp2[s/2] >> ((s & 1) * 16)) & 0xFFFFu;
                acc += (unsigned long long)(rp + 1) * (unsigned long long)(r + 1);
            }
        }
    }

    // ---- exact u64 reduction: wave shuffle + cross-wave (in keys_sh) ----
    #pragma unroll
    for (int off = 32; off > 0; off >>= 1)
        acc += __shfl_down(acc, off, 64);
    __syncthreads();   // all rank-loop keys_sh reads done before reuse
    unsigned long long* wred = (unsigned long long*)keys_sh;
    if (lane == 0) wred[wv] = acc;
    __syncthreads();
    if (tid == 0) {
        unsigned long long S = 0;
        #pragma unroll
        for (int w = 0; w < 16; ++w) S += wred[w];
        double Sd = (double)S;                          // exact (< 2^53)
        double cov = Sd / (double)N_ROWS - 67117056.25; // 8192.5^2
        double denom = 22369621.25 + 2e-6;              // (N^2-1)/12 + 2*EPS
        float contrib = (float)(-(cov / denom) / (double)N_COLS);
        atomicAdd(out, contrib);                        // device-scope
    }
}

extern "C" void kernel_launch(void* const* d_in, const int* in_sizes, int n_in,
                              void* d_out, int out_size, void* d_ws, size_t ws_size,
                              hipStream_t stream) {
    const float* pred   = (const float*)d_in[0];
    const float* target = (const float*)d_in[1];
    float* out = (float*)d_out;

    hipMemsetAsync(out, 0, sizeof(float), stream);   // capture-safe
    spearman_col_kernel<<<N_COLS, NT, 0, stream>>>(pred, target, out);
}

// Round 8
// 315.877 us; speedup vs baseline: 1.1213x; 1.1213x over previous
//
#include <hip/hip_runtime.h>

// SpearmanCorrelationLoss on MI355X (gfx950) — R8
//
// Math: double-argsort ranks are a permutation of 1..N per column, so
// mean/var of ranks are exact constants; only S = Sum(rank_p*rank_t) needed:
//   corr_c = (S/N - 8192.5^2) / ((N^2-1)/12 + 2*EPS),  out = -mean_c(corr_c)
//
// Histogram ranking: bucket = floor(sigmoid(1.702*x)*8192) ~ Gaussian CDF ->
// near-uniform buckets (lambda ~2.15). rank(x) = P[b(x)] + #{y in bucket: y<x}
// (strict-less = lower_bound tie semantics; error ~1e-10 on output).
//
// R8 vs R7 (354 us; FETCH 496 MB = 4x logical because the 16 column-blocks
// sharing each 64 B line drift apart and harness restore/poison drain
// (~500 MB/iter background) thrashes L3): XCD-aware column swizzle
//   col = (blk%8)*64 + blk/8
// With round-robin workgroup->XCD dispatch, XCD x owns blocks == x (mod 8)
// => columns [64x,64x+64): 256 B/row, line-aligned, total 16384*256 B = 4 MB
// = exactly one XCD's private L2. Line reuse (16 cols/line) is then served
// by L2 regardless of L3 state. Kernel body identical to R7.

#define N_ROWS 16384
#define N_COLS 512
#define NT 1024
#define PT 16            // elements per thread
#define NBINS 8192
#define NWORDS (NBINS / 2)   // packed u16 cursor words

__device__ __forceinline__ unsigned f2key(float x) {
    // order-preserving fp32 -> u32 (no NaNs in input)
    unsigned u = __float_as_uint(x);
    return (u & 0x80000000u) ? ~u : (u | 0x80000000u);
}

// monotone approx Gaussian-CDF bucket: sigma(1.702x) = 1/(1+2^(-2.4554x))
__device__ __forceinline__ int f2bucket(float f) {
    float e = __builtin_amdgcn_exp2f(-2.4554f * f);   // v_exp_f32
    float s = __builtin_amdgcn_rcpf(1.0f + e);        // v_rcp_f32
    int b = (int)(s * (float)NBINS);
    return b < 0 ? 0 : (b > NBINS - 1 ? NBINS - 1 : b);
}

__global__ __launch_bounds__(NT, 8)
void spearman_col_kernel(const float* __restrict__ A, const float* __restrict__ B,
                         float* __restrict__ out) {
    __shared__ unsigned cursor[NWORDS];                  // 16 KB (u16-packed)
    __shared__ __align__(16) unsigned keys_sh[N_ROWS];   // 64 KB; total 80 KB
    // XCD-aware swizzle: blocks on the same XCD (round-robin %8) take 64
    // consecutive columns -> their global lines fit that XCD's 4 MB L2.
    const int col = ((blockIdx.x & 7) << 6) | (blockIdx.x >> 3);
    const int tid = threadIdx.x;
    const int lane = tid & 63;
    const int wv = tid >> 6;

    unsigned rp2[PT / 2];          // packed u16 pred ranks (0-based, <16384)
    unsigned long long acc = 0;

    for (int phase = 0; phase < 2; ++phase) {
        const float* src = (phase == 0) ? A : B;

        // ---- load 16 elements (strided; L2-served via swizzle) ----
        unsigned key[PT];
        unsigned bkt2[PT / 2];     // packed u16 buckets
        #pragma unroll
        for (int s = 0; s < PT; s += 2) {
            float f0 = src[(size_t)(tid + (s+0) * NT) * N_COLS + col];
            float f1 = src[(size_t)(tid + (s+1) * NT) * N_COLS + col];
            key[s]   = f2key(f0);
            key[s+1] = f2key(f1);
            bkt2[s/2] = (unsigned)f2bucket(f0) | ((unsigned)f2bucket(f1) << 16);
        }

        // ---- zero packed histogram ----
        __syncthreads();   // previous phase's keys_sh/cursor readers done
        ((uint4*)cursor)[tid] = make_uint4(0u, 0u, 0u, 0u);
        __syncthreads();

        // ---- histogram: +1 into the u16 half of word b>>1 ----
        #pragma unroll
        for (int s = 0; s < PT; ++s) {
            unsigned b = (bkt2[s/2] >> ((s & 1) * 16)) & 0xFFFFu;
            atomicAdd(&cursor[b >> 1], 1u << ((b & 1) * 16));
        }
        __syncthreads();

        // ---- exclusive prefix over 8192 u16 bins, wave-shuffle scan ----
        {
            unsigned* wtot = keys_sh;            // [0..15], keys_sh dead here
            uint4 h = ((uint4*)cursor)[tid];     // 4 words = 8 bins
            unsigned c0 = (h.x & 0xFFFFu), c1 = (h.x >> 16);
            unsigned c2 = (h.y & 0xFFFFu), c3 = (h.y >> 16);
            unsigned c4 = (h.z & 0xFFFFu), c5 = (h.z >> 16);
            unsigned c6 = (h.w & 0xFFFFu), c7 = (h.w >> 16);
            unsigned mysum = c0 + c1 + c2 + c3 + c4 + c5 + c6 + c7;
            unsigned incl = mysum;
            #pragma unroll
            for (int off = 1; off < 64; off <<= 1) {
                unsigned v = __shfl_up(incl, off, 64);
                if (lane >= off) incl += v;
            }
            if (lane == 63) wtot[wv] = incl;
            __syncthreads();
            if (tid < 16) {
                unsigned in2 = wtot[tid];
                #pragma unroll
                for (int off = 1; off < 16; off <<= 1) {
                    unsigned q = __shfl_up(in2, off, 64);
                    if (tid >= off) in2 += q;
                }
                wtot[tid] = in2;
            }
            __syncthreads();
            unsigned r = ((wv == 0) ? 0u : wtot[wv - 1]) + incl - mysum;
            uint4 o;
            o.x = r | ((r + c0) << 16); r += c0 + c1;
            o.y = r | ((r + c2) << 16); r += c2 + c3;
            o.z = r | ((r + c4) << 16); r += c4 + c5;
            o.w = r | ((r + c6) << 16); r += c6 + c7;
            ((uint4*)cursor)[tid] = o;
        }
        __syncthreads();   // wtot reads done before scatter overwrites keys_sh

        // ---- scatter keys into bucket slices (packed-half atomicAdd) ----
        #pragma unroll
        for (int s = 0; s < PT; ++s) {
            unsigned b = (bkt2[s/2] >> ((s & 1) * 16)) & 0xFFFFu;
            unsigned old = atomicAdd(&cursor[b >> 1], 1u << ((b & 1) * 16));
            unsigned slot = (old >> ((b & 1) * 16)) & 0xFFFFu;
            keys_sh[slot] = key[s];
        }
        __syncthreads();   // after this: half b of cursor == P[b+1]

        // ---- rank: P[b] + strict-less count within slice ----
        const unsigned short* cur16 = (const unsigned short*)cursor;
        #pragma unroll
        for (int s = 0; s < PT; ++s) {
            unsigned b = (bkt2[s/2] >> ((s & 1) * 16)) & 0xFFFFu;
            unsigned k = key[s];
            unsigned lo = (b == 0) ? 0u : (unsigned)cur16[b - 1];
            unsigned hi = (unsigned)cur16[b];
            unsigned r = lo;                       // P[b]
            for (unsigned j = lo; j < hi; ++j)
                r += (keys_sh[j] < k) ? 1u : 0u;
            if (phase == 0) {
                if ((s & 1) == 0) rp2[s/2] = r;
                else              rp2[s/2] |= (r << 16);
            } else {
                unsigned rp = (rp2[s/2] >> ((s & 1) * 16)) & 0xFFFFu;
                acc += (unsigned long long)(rp + 1) * (unsigned long long)(r + 1);
            }
        }
    }

    // ---- exact u64 reduction: wave shuffle + cross-wave (in keys_sh) ----
    #pragma unroll
    for (int off = 32; off > 0; off >>= 1)
        acc += __shfl_down(acc, off, 64);
    __syncthreads();   // all rank-loop keys_sh reads done before reuse
    unsigned long long* wred = (unsigned long long*)keys_sh;
    if (lane == 0) wred[wv] = acc;
    __syncthreads();
    if (tid == 0) {
        unsigned long long S = 0;
        #pragma unroll
        for (int w = 0; w < 16; ++w) S += wred[w];
        double Sd = (double)S;                          // exact (< 2^53)
        double cov = Sd / (double)N_ROWS - 67117056.25; // 8192.5^2
        double denom = 22369621.25 + 2e-6;              // (N^2-1)/12 + 2*EPS
        float contrib = (float)(-(cov / denom) / (double)N_COLS);
        atomicAdd(out, contrib);                        // device-scope
    }
}

extern "C" void kernel_launch(void* const* d_in, const int* in_sizes, int n_in,
                              void* d_out, int out_size, void* d_ws, size_t ws_size,
                              hipStream_t stream) {
    const float* pred   = (const float*)d_in[0];
    const float* target = (const float*)d_in[1];
    float* out = (float*)d_out;

    hipMemsetAsync(out, 0, sizeof(float), stream);   // capture-safe
    spearman_col_kernel<<<N_COLS, NT, 0, stream>>>(pred, target, out);
}

// Round 9
// 233.238 us; speedup vs baseline: 1.5187x; 1.3543x over previous
//
#include <hip/hip_runtime.h>

// SpearmanCorrelationLoss on MI355X (gfx950) — R9
//
// Math: double-argsort ranks are a permutation of 1..N per column, so
// mean/var of ranks are exact constants; only S = Sum(rank_p*rank_t) needed:
//   corr_c = (S/N - 8192.5^2) / ((N^2-1)/12 + 2*EPS),  out = -mean_c(corr_c)
//
// Histogram ranking: bucket = floor(sigmoid(1.702*x)*8192) ~ Gaussian CDF ->
// near-uniform buckets (lambda ~2.15). rank(x) = P[b(x)] + #{y in bucket: y<x}.
//
// R9 vs R8 (316 us): R8 proved the no-transpose path is VMEM-transaction-rate
// bound (~7 cyc per divergent lane-request, 65536/CU -> ~200 us floor;
// VALUBusy 14%). Only coalescing fixes that -> transpose returns. R6's flaw
// (main kernel FETCH 197 MB: L3 evicted transposed data between dispatches)
// is attacked with an XCD-aligned handoff: transpose grid (8,256,2) puts
// column-group x on XCD x (linear%8==bx); main kernel swizzle
// col=(b%8)*64+b/8 reads group x on XCD x -> producer-L2 -> consumer-L2,
// independent of L3 state.

#define N_ROWS 16384
#define N_COLS 512
#define NT 1024
#define PT 16            // elements per thread
#define NBINS 8192
#define NWORDS (NBINS / 2)   // packed u16 cursor words

__device__ __forceinline__ unsigned f2key(float x) {
    // order-preserving fp32 -> u32 (no NaNs in input)
    unsigned u = __float_as_uint(x);
    return (u & 0x80000000u) ? ~u : (u | 0x80000000u);
}

// monotone approx Gaussian-CDF bucket: sigma(1.702x) = 1/(1+2^(-2.4554x))
__device__ __forceinline__ int f2bucket(float f) {
    float e = __builtin_amdgcn_exp2f(-2.4554f * f);   // v_exp_f32
    float s = __builtin_amdgcn_rcpf(1.0f + e);        // v_rcp_f32
    int b = (int)(s * (float)NBINS);
    return b < 0 ? 0 : (b > NBINS - 1 ? NBINS - 1 : b);
}

template <int TRANSPOSED>
__global__ __launch_bounds__(NT, 8)
void spearman_col_kernel(const float* __restrict__ A, const float* __restrict__ B,
                         float* __restrict__ out) {
    __shared__ unsigned cursor[NWORDS];                  // 16 KB (u16-packed)
    __shared__ __align__(16) unsigned keys_sh[N_ROWS];   // 64 KB; total 80 KB
    // XCD swizzle: block b (round-robin XCD b%8) takes column group b%8 ->
    // matches the transpose kernel's producer XCD for L2-resident handoff.
    const int col = ((blockIdx.x & 7) << 6) | (blockIdx.x >> 3);
    const int tid = threadIdx.x;
    const int lane = tid & 63;
    const int wv = tid >> 6;

    unsigned rp2[PT / 2];          // packed u16 pred ranks (0-based, <16384)
    unsigned long long acc = 0;

    for (int phase = 0; phase < 2; ++phase) {
        const float* src = (phase == 0) ? A : B;

        // ---- load 16 elements; keys + buckets in registers ----
        unsigned key[PT];
        unsigned bkt2[PT / 2];     // packed u16 buckets
        if (TRANSPOSED) {
            const float4* colp = (const float4*)(src + (size_t)col * N_ROWS);
            #pragma unroll
            for (int m = 0; m < 4; ++m) {
                float4 f = colp[tid + m * NT];   // 16B/lane, coalesced
                key[4*m+0] = f2key(f.x); key[4*m+1] = f2key(f.y);
                key[4*m+2] = f2key(f.z); key[4*m+3] = f2key(f.w);
                bkt2[2*m+0] = (unsigned)f2bucket(f.x) | ((unsigned)f2bucket(f.y) << 16);
                bkt2[2*m+1] = (unsigned)f2bucket(f.z) | ((unsigned)f2bucket(f.w) << 16);
            }
        } else {
            #pragma unroll
            for (int s = 0; s < PT; s += 2) {
                float f0 = src[(size_t)(tid + (s+0) * NT) * N_COLS + col];
                float f1 = src[(size_t)(tid + (s+1) * NT) * N_COLS + col];
                key[s]   = f2key(f0);
                key[s+1] = f2key(f1);
                bkt2[s/2] = (unsigned)f2bucket(f0) | ((unsigned)f2bucket(f1) << 16);
            }
        }

        // ---- zero packed histogram ----
        __syncthreads();   // previous phase's keys_sh/cursor readers done
        ((uint4*)cursor)[tid] = make_uint4(0u, 0u, 0u, 0u);
        __syncthreads();

        // ---- histogram: +1 into the u16 half of word b>>1 ----
        #pragma unroll
        for (int s = 0; s < PT; ++s) {
            unsigned b = (bkt2[s/2] >> ((s & 1) * 16)) & 0xFFFFu;
            atomicAdd(&cursor[b >> 1], 1u << ((b & 1) * 16));
        }
        __syncthreads();

        // ---- exclusive prefix over 8192 u16 bins, wave-shuffle scan ----
        {
            unsigned* wtot = keys_sh;            // [0..15], keys_sh dead here
            uint4 h = ((uint4*)cursor)[tid];     // 4 words = 8 bins
            unsigned c0 = (h.x & 0xFFFFu), c1 = (h.x >> 16);
            unsigned c2 = (h.y & 0xFFFFu), c3 = (h.y >> 16);
            unsigned c4 = (h.z & 0xFFFFu), c5 = (h.z >> 16);
            unsigned c6 = (h.w & 0xFFFFu), c7 = (h.w >> 16);
            unsigned mysum = c0 + c1 + c2 + c3 + c4 + c5 + c6 + c7;
            unsigned incl = mysum;
            #pragma unroll
            for (int off = 1; off < 64; off <<= 1) {
                unsigned v = __shfl_up(incl, off, 64);
                if (lane >= off) incl += v;
            }
            if (lane == 63) wtot[wv] = incl;
            __syncthreads();
            if (tid < 16) {
                unsigned in2 = wtot[tid];
                #pragma unroll
                for (int off = 1; off < 16; off <<= 1) {
                    unsigned q = __shfl_up(in2, off, 64);
                    if (tid >= off) in2 += q;
                }
                wtot[tid] = in2;
            }
            __syncthreads();
            unsigned r = ((wv == 0) ? 0u : wtot[wv - 1]) + incl - mysum;
            uint4 o;
            o.x = r | ((r + c0) << 16); r += c0 + c1;
            o.y = r | ((r + c2) << 16); r += c2 + c3;
            o.z = r | ((r + c4) << 16); r += c4 + c5;
            o.w = r | ((r + c6) << 16); r += c6 + c7;
            ((uint4*)cursor)[tid] = o;
        }
        __syncthreads();   // wtot reads done before scatter overwrites keys_sh

        // ---- scatter keys into bucket slices (packed-half atomicAdd) ----
        #pragma unroll
        for (int s = 0; s < PT; ++s) {
            unsigned b = (bkt2[s/2] >> ((s & 1) * 16)) & 0xFFFFu;
            unsigned old = atomicAdd(&cursor[b >> 1], 1u << ((b & 1) * 16));
            unsigned slot = (old >> ((b & 1) * 16)) & 0xFFFFu;
            keys_sh[slot] = key[s];
        }
        __syncthreads();   // after this: half b of cursor == P[b+1]

        // ---- rank: P[b] + strict-less count within slice ----
        const unsigned short* cur16 = (const unsigned short*)cursor;
        #pragma unroll
        for (int s = 0; s < PT; ++s) {
            unsigned b = (bkt2[s/2] >> ((s & 1) * 16)) & 0xFFFFu;
            unsigned k = key[s];
            unsigned lo = (b == 0) ? 0u : (unsigned)cur16[b - 1];
            unsigned hi = (unsigned)cur16[b];
            unsigned r = lo;                       // P[b]
            for (unsigned j = lo; j < hi; ++j)
                r += (keys_sh[j] < k) ? 1u : 0u;
            if (phase == 0) {
                if ((s & 1) == 0) rp2[s/2] = r;
                else              rp2[s/2] |= (r << 16);
            } else {
                unsigned rp = (rp2[s/2] >> ((s & 1) * 16)) & 0xFFFFu;
                acc += (unsigned long long)(rp + 1) * (unsigned long long)(r + 1);
            }
        }
    }

    // ---- exact u64 reduction: wave shuffle + cross-wave (in keys_sh) ----
    #pragma unroll
    for (int off = 32; off > 0; off >>= 1)
        acc += __shfl_down(acc, off, 64);
    __syncthreads();   // all rank-loop keys_sh reads done before reuse
    unsigned long long* wred = (unsigned long long*)keys_sh;
    if (lane == 0) wred[wv] = acc;
    __syncthreads();
    if (tid == 0) {
        unsigned long long S = 0;
        #pragma unroll
        for (int w = 0; w < 16; ++w) S += wred[w];
        double Sd = (double)S;                          // exact (< 2^53)
        double cov = Sd / (double)N_ROWS - 67117056.25; // 8192.5^2
        double denom = 22369621.25 + 2e-6;              // (N^2-1)/12 + 2*EPS
        float contrib = (float)(-(cov / denom) / (double)N_COLS);
        atomicAdd(out, contrib);                        // device-scope
    }
}

// 64x64 tile transpose, XCD-aligned: grid (8, 256, 2). bx = column group ->
// linear block index % 8 == bx -> XCD bx produces columns [64bx, 64bx+64),
// which the main kernel consumes on the same XCD.
__global__ __launch_bounds__(256)
void transpose_kernel(const float* __restrict__ in0, const float* __restrict__ in1,
                      float* __restrict__ out0, float* __restrict__ out1) {
    __shared__ float tile[64][65];
    const float* in  = blockIdx.z ? in1 : in0;
    float* out       = blockIdx.z ? out1 : out0;
    const int c0 = blockIdx.x * 64;   // column group (XCD-aligned)
    const int r0 = blockIdx.y * 64;   // row group
    const int t = threadIdx.x;
    const int cg = (t & 15) * 4;
    const int rr = t >> 4;
    #pragma unroll
    for (int it = 0; it < 4; ++it) {
        int r = rr + it * 16;
        float4 f = *(const float4*)&in[(size_t)(r0 + r) * N_COLS + c0 + cg];
        tile[r][cg + 0] = f.x; tile[r][cg + 1] = f.y;
        tile[r][cg + 2] = f.z; tile[r][cg + 3] = f.w;
    }
    __syncthreads();
    const int rg = (t & 15) * 4;
    const int cc = t >> 4;
    #pragma unroll
    for (int it = 0; it < 4; ++it) {
        int c = cc + it * 16;
        float4 f;
        f.x = tile[rg + 0][c]; f.y = tile[rg + 1][c];
        f.z = tile[rg + 2][c]; f.w = tile[rg + 3][c];
        *(float4*)&out[(size_t)(c0 + c) * N_ROWS + r0 + rg] = f;
    }
}

extern "C" void kernel_launch(void* const* d_in, const int* in_sizes, int n_in,
                              void* d_out, int out_size, void* d_ws, size_t ws_size,
                              hipStream_t stream) {
    const float* pred   = (const float*)d_in[0];
    const float* target = (const float*)d_in[1];
    float* out = (float*)d_out;

    const size_t mat_bytes = (size_t)N_ROWS * N_COLS * sizeof(float);
    float* predT   = (float*)d_ws;
    float* targetT = predT + (size_t)N_ROWS * N_COLS;

    hipMemsetAsync(out, 0, sizeof(float), stream);   // capture-safe

    if (ws_size >= 2 * mat_bytes) {
        dim3 tgrid(N_COLS / 64, N_ROWS / 64, 2);     // bx = column group
        transpose_kernel<<<tgrid, 256, 0, stream>>>(pred, target, predT, targetT);
        spearman_col_kernel<1><<<N_COLS, NT, 0, stream>>>(predT, targetT, out);
    } else {
        spearman_col_kernel<0><<<N_COLS, NT, 0, stream>>>(pred, target, out);
    }
}